// Round 1
// baseline (844.470 us; speedup 1.0000x reference)
//
#include <hip/hip_runtime.h>
#include <hip/hip_bf16.h>
#include <stdint.h>

#define DI __device__ __forceinline__

typedef unsigned short u16;
typedef unsigned int   u32;

DI float bf2f(u32 v){ u32 x = v << 16; float f; __builtin_memcpy(&f, &x, 4); return f; }
DI u16 f2bf(float f){ u32 x; __builtin_memcpy(&x, &f, 4); u32 r = (x + 0x7fffu + ((x >> 16) & 1u)) >> 16; return (u16)r; }

DI void unpack8(uint4 v, float* f){
  f[0]=bf2f(v.x & 0xffffu); f[1]=bf2f(v.x >> 16);
  f[2]=bf2f(v.y & 0xffffu); f[3]=bf2f(v.y >> 16);
  f[4]=bf2f(v.z & 0xffffu); f[5]=bf2f(v.z >> 16);
  f[6]=bf2f(v.w & 0xffffu); f[7]=bf2f(v.w >> 16);
}

// ---------------- K1: fused depthwise convs + pointwise for k_x ----------------
DI void load_row18(const float* p, bool rowv, bool leftv, bool rightv, float* r){
  if(rowv){
    const float4* p4 = (const float4*)p;
    #pragma unroll
    for(int q=0;q<4;q++){ float4 v = p4[q]; r[1+4*q]=v.x; r[2+4*q]=v.y; r[3+4*q]=v.z; r[4+4*q]=v.w; }
    r[0]  = leftv  ? p[-1] : 0.f;
    r[17] = rightv ? p[16] : 0.f;
  } else {
    #pragma unroll
    for(int q=0;q<18;q++) r[q]=0.f;
  }
}
DI void load_row18_add(const float* p, bool rowv, bool leftv, bool rightv, float* r){
  if(rowv){
    const float4* p4 = (const float4*)p;
    #pragma unroll
    for(int q=0;q<4;q++){ float4 v = p4[q]; r[1+4*q]+=v.x; r[2+4*q]+=v.y; r[3+4*q]+=v.z; r[4+4*q]+=v.w; }
    if(leftv)  r[0]  += p[-1];
    if(rightv) r[17] += p[16];
  }
}
DI void conv16(const float r[3][18], const float* w, float* y){
  #pragma unroll
  for(int p=0;p<16;p++){
    float s =      r[0][p]   * w[0];
    s = fmaf(r[0][p+1], w[1], s);
    s = fmaf(r[0][p+2], w[2], s);
    s = fmaf(r[1][p],   w[3], s);
    s = fmaf(r[1][p+1], w[4], s);
    s = fmaf(r[1][p+2], w[5], s);
    s = fmaf(r[2][p],   w[6], s);
    s = fmaf(r[2][p+1], w[7], s);
    s = fmaf(r[2][p+2], w[8], s);
    y[p] = s;
  }
}
DI void store16bf(u16* p, const float* y, float add){
  #pragma unroll
  for(int h=0;h<2;h++){
    union { u16 s[8]; uint4 v; } pk;
    #pragma unroll
    for(int q=0;q<8;q++) pk.s[q] = f2bf(y[h*8+q] + add);
    ((uint4*)p)[h] = pk.v;
  }
}

__global__ __launch_bounds__(256) void k1_dsc(
    const float* __restrict__ x, const float* __restrict__ mask_, const float* __restrict__ avg,
    const float* __restrict__ dwq, const float* __restrict__ dbq,
    const float* __restrict__ dwk, const float* __restrict__ dbk,
    const float* __restrict__ pwk, const float* __restrict__ pbk,
    const float* __restrict__ dwv, const float* __restrict__ dbv,
    u16* __restrict__ Dqx, u16* __restrict__ Dqm, u16* __restrict__ Kx, u16* __restrict__ Dvs)
{
  __shared__ __align__(16) float dwkL[64*68];
  __shared__ __align__(16) float pwTL[64*68];
  int t = threadIdx.x;
  int bid = blockIdx.x;
  int tile = bid & 3, iw = (bid>>2)&255, b = bid>>10;

  for(int idx=t; idx<4096; idx+=256)
    pwTL[(idx&63)*68 + (idx>>6)] = pwk[idx];   // pwT[a][o] = pw[o][a]

  int ch = t>>2, pg = t&3;
  int ih0 = tile*64 + pg*16;
  bool leftv = ih0 > 0, rightv = ih0 < 240;
  long base = ((long)(b*64+ch)<<16) + (iw<<8) + ih0;
  bool r0v = iw > 0, r2v = iw < 255;

  float rx[3][18];
  load_row18(x + base - 256, r0v, leftv, rightv, rx[0]);
  load_row18(x + base,       true, leftv, rightv, rx[1]);
  load_row18(x + base + 256, r2v, leftv, rightv, rx[2]);
  float y[16];
  { float w[9];
    #pragma unroll
    for(int q=0;q<9;q++) w[q]=dwq[ch*9+q];
    conv16(rx, w, y); store16bf(Dqx + base, y, dbq[ch]); }
  { float w[9];
    #pragma unroll
    for(int q=0;q<9;q++) w[q]=dwk[ch*9+q];
    conv16(rx, w, y);
    float bk = dbk[ch];
    #pragma unroll
    for(int p=0;p<16;p++) dwkL[ch*68 + pg*16 + p] = y[p] + bk; }
  // x + avg_ct  -> depthwise v (biases doubled: v_x + v_a)
  load_row18_add(avg + base - 256, r0v, leftv, rightv, rx[0]);
  load_row18_add(avg + base,       true, leftv, rightv, rx[1]);
  load_row18_add(avg + base + 256, r2v, leftv, rightv, rx[2]);
  { float w[9];
    #pragma unroll
    for(int q=0;q<9;q++) w[q]=dwv[ch*9+q];
    conv16(rx, w, y); store16bf(Dvs + base, y, 2.f*dbv[ch]); }
  // mask -> depthwise q
  load_row18(mask_ + base - 256, r0v, leftv, rightv, rx[0]);
  load_row18(mask_ + base,       true, leftv, rightv, rx[1]);
  load_row18(mask_ + base + 256, r2v, leftv, rightv, rx[2]);
  { float w[9];
    #pragma unroll
    for(int q=0;q<9;q++) w[q]=dwq[ch*9+q];
    conv16(rx, w, y); store16bf(Dqm + base, y, dbq[ch]); }

  __syncthreads();
  // pointwise 64x64 for k_x only
  int o0 = (t>>4)*4, px0 = (t&15)*4;
  float acc[4][4];
  #pragma unroll
  for(int oo=0;oo<4;oo++){ float pb = pbk[o0+oo];
    #pragma unroll
    for(int pp=0;pp<4;pp++) acc[oo][pp]=pb; }
  for(int a=0;a<64;a++){
    float4 pv4 = *(const float4*)(pwTL + a*68 + o0);
    float4 dv4 = *(const float4*)(dwkL + a*68 + px0);
    float pv[4]={pv4.x,pv4.y,pv4.z,pv4.w};
    float dv[4]={dv4.x,dv4.y,dv4.z,dv4.w};
    #pragma unroll
    for(int oo=0;oo<4;oo++)
      #pragma unroll
      for(int pp=0;pp<4;pp++) acc[oo][pp] = fmaf(pv[oo], dv[pp], acc[oo][pp]);
  }
  #pragma unroll
  for(int oo=0;oo<4;oo++){
    union{ u16 s[4]; uint2 v; } pk;
    #pragma unroll
    for(int pp=0;pp<4;pp++) pk.s[pp] = f2bf(acc[oo][pp]);
    long kb = ((long)(b*64+o0+oo)<<16) + (iw<<8) + tile*64 + px0;
    *(uint2*)(Kx + kb) = pk.v;
  }
}

// ---------------- K2: scrambled QK GEMMs, per-block partials ----------------
__global__ __launch_bounds__(256) void k2_qk(
    const u16* __restrict__ Dqx, const u16* __restrict__ Dqm, const u16* __restrict__ Kx,
    float* __restrict__ part, float* __restrict__ part_r)
{
  __shared__ __align__(16) float q1L[64*68];
  __shared__ __align__(16) float q2L[64*68];
  __shared__ __align__(16) float kcL[64*68];
  __shared__ float rbuf[4*64];
  int t = threadIdx.x;
  int pb = blockIdx.x;
  int uh = pb & 1, ch = (pb>>1)&63, b = pb>>7;
  int li = t>>2, lu0 = (t&3)*16;
  long qoff = ((long)(b*64+li)<<16) + (ch<<10) + uh*512;
  long koff = ((long)(b*64+ch)<<16) + (long)(uh*512)*64;
  float acc1[4][4] = {{0}}; float acc2[4][4] = {{0}};
  float rs[16];
  #pragma unroll
  for(int m=0;m<16;m++) rs[m]=0.f;

  for(int c0=0;c0<8;c0++){
    int u0 = c0*64;
    if(c0) __syncthreads();
    { const uint4* p = (const uint4*)(Dqx + qoff + u0 + lu0);
      float f[16]; unpack8(p[0], f); unpack8(p[1], f+8);
      #pragma unroll
      for(int m=0;m<16;m++) q1L[(lu0+m)*68 + li] = f[m]; }
    { const uint4* p = (const uint4*)(Dqm + qoff + u0 + lu0);
      float f[16]; unpack8(p[0], f); unpack8(p[1], f+8);
      #pragma unroll
      for(int m=0;m<16;m++) q2L[(lu0+m)*68 + li] = f[m]; }
    { const uint4* p = (const uint4*)(Kx + koff + (long)((u0 + li)*64 + lu0));
      float f[16]; unpack8(p[0], f); unpack8(p[1], f+8);
      float* dst = kcL + li*68 + lu0;
      *(float4*)(dst)    = make_float4(f[0],f[1],f[2],f[3]);
      *(float4*)(dst+4)  = make_float4(f[4],f[5],f[6],f[7]);
      *(float4*)(dst+8)  = make_float4(f[8],f[9],f[10],f[11]);
      *(float4*)(dst+12) = make_float4(f[12],f[13],f[14],f[15]);
      #pragma unroll
      for(int m=0;m<16;m++) rs[m] += f[m]; }
    __syncthreads();
    int i0 = (t>>4)*4, j0 = (t&15)*4;
    #pragma unroll 8
    for(int uu=0; uu<64; uu++){
      float4 kv4 = *(const float4*)(kcL + uu*68 + j0);
      float4 q14 = *(const float4*)(q1L + uu*68 + i0);
      float4 q24 = *(const float4*)(q2L + uu*68 + i0);
      float kv[4]={kv4.x,kv4.y,kv4.z,kv4.w};
      float q1[4]={q14.x,q14.y,q14.z,q14.w};
      float q2[4]={q24.x,q24.y,q24.z,q24.w};
      #pragma unroll
      for(int ii=0;ii<4;ii++)
        #pragma unroll
        for(int jj=0;jj<4;jj++){
          acc1[ii][jj] = fmaf(q1[ii], kv[jj], acc1[ii][jj]);
          acc2[ii][jj] = fmaf(q2[ii], kv[jj], acc2[ii][jj]);
        }
    }
  }
  { int i0 = (t>>4)*4, j0 = (t&15)*4;
    float* p1 = part + ((long)pb*2)*4096;
    float* p2 = p1 + 4096;
    #pragma unroll
    for(int ii=0;ii<4;ii++){
      *(float4*)(p1 + (i0+ii)*64 + j0) = make_float4(acc1[ii][0],acc1[ii][1],acc1[ii][2],acc1[ii][3]);
      *(float4*)(p2 + (i0+ii)*64 + j0) = make_float4(acc2[ii][0],acc2[ii][1],acc2[ii][2],acc2[ii][3]);
    } }
  // column sums of this block's K slice (for the pb_q * colsum(B) bias term)
  #pragma unroll
  for(int off=4; off<64; off<<=1)
    #pragma unroll
    for(int m=0;m<16;m++) rs[m] += __shfl_xor(rs[m], off);
  if((t&63) < 4){
    int wv = t>>6, jg = t&3;
    #pragma unroll
    for(int m=0;m<16;m++) rbuf[wv*64 + jg*16 + m] = rs[m];
  }
  __syncthreads();
  if(t < 64)
    part_r[(long)pb*64 + t] = rbuf[t] + rbuf[64+t] + rbuf[128+t] + rbuf[192+t];
}

// ---------------- K2b: reduce partials ----------------
__global__ __launch_bounds__(256) void k2b_reduce(
    const float* __restrict__ part, const float* __restrict__ part_r,
    float* __restrict__ M1, float* __restrict__ M2, float* __restrict__ rsum)
{
  int t = threadIdx.x;
  int blk = blockIdx.x;
  if(blk < 256){
    int e = blk*256 + t;
    int mat = e >> 15;
    int b = (e >> 12) & 7;
    int ij = e & 4095;
    float s = 0.f;
    const float* p = part + ((long)b*256 + mat)*4096 + ij;
    for(int cu=0; cu<128; cu++) s += p[(long)cu*8192];
    (mat ? M2 : M1)[b*4096 + ij] = s;
  } else {
    for(int e=t; e<512; e+=256){
      int bb = e>>6, j = e&63;
      float s=0.f;
      const float* p = part_r + (long)bb*8192 + j;
      for(int cu=0;cu<128;cu++) s += p[cu*64];
      rsum[bb*64 + j] = s;
    }
  }
}

// ---------------- K3: bias fixups + flat softmax + S=A1+A2, T=S*PWv ----------------
__global__ __launch_bounds__(256) void k3_small(
    const float* __restrict__ M1, const float* __restrict__ M2, const float* __restrict__ rsum,
    const float* __restrict__ pwq, const float* __restrict__ pbq,
    const float* __restrict__ pwv, const float* __restrict__ pbv,
    float* __restrict__ Tt, float* __restrict__ cvec)
{
  __shared__ __align__(16) float ML[64*68];
  __shared__ __align__(16) float SL[64*68];
  __shared__ float red[8];
  __shared__ float rL[64];
  int b = blockIdx.x, t = threadIdx.x;
  if(t < 64) rL[t] = rsum[b*64 + t];
  int i = t>>2, j0 = (t&3)*16;
  float pq = pbq[i];
  for(int m=0; m<2; m++){
    const float* M = (m ? M2 : M1) + b*4096;
    __syncthreads();
    for(int idx=t; idx<4096; idx+=256)
      ML[(idx>>6)*68 + (idx&63)] = M[idx];
    __syncthreads();
    float l[16];
    #pragma unroll
    for(int q=0;q<16;q++) l[q] = pq * rL[j0+q];
    for(int a=0;a<64;a++){
      float w = pwq[i*64 + a];
      #pragma unroll
      for(int q=0;q<16;q++) l[q] = fmaf(w, ML[a*68 + j0 + q], l[q]);
    }
    float mx = -1e30f;
    #pragma unroll
    for(int q=0;q<16;q++){ l[q] *= 0.00390625f; mx = fmaxf(mx, l[q]); }
    for(int off=1; off<64; off<<=1) mx = fmaxf(mx, __shfl_xor(mx, off));
    if((t&63)==0) red[t>>6] = mx;
    __syncthreads();
    mx = fmaxf(fmaxf(red[0],red[1]), fmaxf(red[2],red[3]));
    float e[16]; float s = 0.f;
    #pragma unroll
    for(int q=0;q<16;q++){ e[q] = __expf(l[q]-mx); s += e[q]; }
    for(int off=1; off<64; off<<=1) s += __shfl_xor(s, off);
    if((t&63)==0) red[4 + (t>>6)] = s;
    __syncthreads();
    float inv = 1.f / (red[4]+red[5]+red[6]+red[7]);
    if(m==0){
      #pragma unroll
      for(int q=0;q<16;q++) SL[i*68 + j0 + q] = e[q]*inv;
    } else {
      #pragma unroll
      for(int q=0;q<16;q++) SL[i*68 + j0 + q] += e[q]*inv;
    }
  }
  __syncthreads();
  int a0 = (t&3)*16;
  float tacc[16];
  #pragma unroll
  for(int q=0;q<16;q++) tacc[q]=0.f;
  float cv = 0.f;
  for(int j=0;j<64;j++){
    float sij = SL[i*68 + j];
    const float* pr = pwv + j*64 + a0;
    #pragma unroll
    for(int q=0;q<16;q++) tacc[q] = fmaf(sij, pr[q], tacc[q]);
    cv = fmaf(sij, pbv[j], cv);
  }
  #pragma unroll
  for(int q=0;q<16;q++) Tt[b*4096 + (a0+q)*64 + i] = tacc[q];   // stored transposed [a][i]
  if((t&3)==0) cvec[b*64 + i] = 2.f*cv;
}

// ---------------- K4: out = T*Dvs + cvec + x ----------------
__global__ __launch_bounds__(256) void k4_out(
    const u16* __restrict__ Dvs, const float* __restrict__ Tt, const float* __restrict__ cvec,
    const float* __restrict__ x, float* __restrict__ out)
{
  __shared__ __align__(16) float TT[64*68];
  __shared__ __align__(16) float DL[64*68];
  __shared__ float cvL[64];
  int t = threadIdx.x;
  int bid = blockIdx.x;
  int tile = bid & 3, iw = (bid>>2)&255, b = bid>>10;
  int s0 = (iw<<8) + tile*64;
  if(t < 64) cvL[t] = cvec[b*64 + t];
  { int a = t>>2, ii0 = (t&3)*16;
    const float4* p = (const float4*)(Tt + b*4096 + a*64 + ii0);
    float4* d = (float4*)(TT + a*68 + ii0);
    d[0]=p[0]; d[1]=p[1]; d[2]=p[2]; d[3]=p[3]; }
  { int a = t>>2, pp0 = (t&3)*16;
    const uint4* p = (const uint4*)(Dvs + ((long)(b*64+a)<<16) + s0 + pp0);
    float f[16]; unpack8(p[0], f); unpack8(p[1], f+8);
    float* d = DL + a*68 + pp0;
    *(float4*)(d)    = make_float4(f[0],f[1],f[2],f[3]);
    *(float4*)(d+4)  = make_float4(f[4],f[5],f[6],f[7]);
    *(float4*)(d+8)  = make_float4(f[8],f[9],f[10],f[11]);
    *(float4*)(d+12) = make_float4(f[12],f[13],f[14],f[15]); }
  __syncthreads();
  int i0 = (t>>4)*4, p0 = (t&15)*4;
  float acc[4][4] = {{0}};
  for(int a=0;a<64;a++){
    float4 tv4 = *(const float4*)(TT + a*68 + i0);
    float4 dv4 = *(const float4*)(DL + a*68 + p0);
    float tv[4]={tv4.x,tv4.y,tv4.z,tv4.w};
    float dv[4]={dv4.x,dv4.y,dv4.z,dv4.w};
    #pragma unroll
    for(int ii=0;ii<4;ii++)
      #pragma unroll
      for(int pp=0;pp<4;pp++) acc[ii][pp] = fmaf(tv[ii], dv[pp], acc[ii][pp]);
  }
  #pragma unroll
  for(int ii=0;ii<4;ii++){
    int row = i0+ii;
    long g = ((long)(b*64+row)<<16) + s0 + p0;
    float4 xv = *(const float4*)(x + g);
    float cv = cvL[row];
    float4 o;
    o.x = acc[ii][0] + cv + xv.x;
    o.y = acc[ii][1] + cv + xv.y;
    o.z = acc[ii][2] + cv + xv.z;
    o.w = acc[ii][3] + cv + xv.w;
    *(float4*)(out + g) = o;
  }
}

extern "C" void kernel_launch(void* const* d_in, const int* in_sizes, int n_in,
                              void* d_out, int out_size, void* d_ws, size_t ws_size,
                              hipStream_t stream)
{
  const float* x    = (const float*)d_in[0];
  const float* mask = (const float*)d_in[1];
  const float* avg  = (const float*)d_in[2];
  const float* dwq  = (const float*)d_in[3];
  const float* dbq  = (const float*)d_in[4];
  const float* pwq  = (const float*)d_in[5];
  const float* pbq  = (const float*)d_in[6];
  const float* dwk  = (const float*)d_in[7];
  const float* dbk  = (const float*)d_in[8];
  const float* pwk  = (const float*)d_in[9];
  const float* pbk  = (const float*)d_in[10];
  const float* dwv  = (const float*)d_in[11];
  const float* dbv  = (const float*)d_in[12];
  const float* pwv  = (const float*)d_in[13];
  const float* pbv  = (const float*)d_in[14];
  float* out = (float*)d_out;
  char* ws = (char*)d_ws;

  u16* Dqx     = (u16*)(ws);
  u16* Dqm     = (u16*)(ws + 67108864);
  u16* Kx      = (u16*)(ws + 134217728);
  u16* Dvs     = (u16*)(ws + 201326592);
  float* part   = (float*)(ws + 268435456);  // 1024 blocks x 2 x 4096
  float* part_r = (float*)(ws + 301989888);  // 1024 x 64
  float* M1     = (float*)(ws + 302252032);
  float* M2     = (float*)(ws + 302383104);
  float* rsum   = (float*)(ws + 302514176);
  float* Tt     = (float*)(ws + 302516224);
  float* cvec   = (float*)(ws + 302647296);

  hipLaunchKernelGGL(k1_dsc, dim3(8192), dim3(256), 0, stream,
      x, mask, avg, dwq, dbq, dwk, dbk, pwk, pbk, dwv, dbv, Dqx, Dqm, Kx, Dvs);
  hipLaunchKernelGGL(k2_qk, dim3(1024), dim3(256), 0, stream, Dqx, Dqm, Kx, part, part_r);
  hipLaunchKernelGGL(k2b_reduce, dim3(257), dim3(256), 0, stream, part, part_r, M1, M2, rsum);
  hipLaunchKernelGGL(k3_small, dim3(8), dim3(256), 0, stream, M1, M2, rsum, pwq, pbq, pwv, pbv, Tt, cvec);
  hipLaunchKernelGGL(k4_out, dim3(8192), dim3(256), 0, stream, Dvs, Tt, cvec, x, out);
}

// Round 2
// 817.328 us; speedup vs baseline: 1.0332x; 1.0332x over previous
//
#include <hip/hip_runtime.h>
#include <hip/hip_bf16.h>
#include <stdint.h>

#define DI __device__ __forceinline__

typedef unsigned short u16;
typedef unsigned int   u32;
typedef __attribute__((ext_vector_type(8))) short short8;
typedef __attribute__((ext_vector_type(4))) float f32x4;

DI float bf2f(u32 v){ u32 x = v << 16; float f; __builtin_memcpy(&f, &x, 4); return f; }
DI u16 f2bf(float f){ u32 x; __builtin_memcpy(&x, &f, 4); u32 r = (x + 0x7fffu + ((x >> 16) & 1u)) >> 16; return (u16)r; }

// ---------------- K1: fused depthwise convs + pointwise for k_x ----------------
DI void load_row18(const float* p, bool rowv, bool leftv, bool rightv, float* r){
  if(rowv){
    const float4* p4 = (const float4*)p;
    #pragma unroll
    for(int q=0;q<4;q++){ float4 v = p4[q]; r[1+4*q]=v.x; r[2+4*q]=v.y; r[3+4*q]=v.z; r[4+4*q]=v.w; }
    r[0]  = leftv  ? p[-1] : 0.f;
    r[17] = rightv ? p[16] : 0.f;
  } else {
    #pragma unroll
    for(int q=0;q<18;q++) r[q]=0.f;
  }
}
DI void load_row18_add(const float* p, bool rowv, bool leftv, bool rightv, float* r){
  if(rowv){
    const float4* p4 = (const float4*)p;
    #pragma unroll
    for(int q=0;q<4;q++){ float4 v = p4[q]; r[1+4*q]+=v.x; r[2+4*q]+=v.y; r[3+4*q]+=v.z; r[4+4*q]+=v.w; }
    if(leftv)  r[0]  += p[-1];
    if(rightv) r[17] += p[16];
  }
}
DI void conv16(const float r[3][18], const float* w, float* y){
  #pragma unroll
  for(int p=0;p<16;p++){
    float s =      r[0][p]   * w[0];
    s = fmaf(r[0][p+1], w[1], s);
    s = fmaf(r[0][p+2], w[2], s);
    s = fmaf(r[1][p],   w[3], s);
    s = fmaf(r[1][p+1], w[4], s);
    s = fmaf(r[1][p+2], w[5], s);
    s = fmaf(r[2][p],   w[6], s);
    s = fmaf(r[2][p+1], w[7], s);
    s = fmaf(r[2][p+2], w[8], s);
    y[p] = s;
  }
}
DI void store16bf(u16* p, const float* y, float add){
  #pragma unroll
  for(int h=0;h<2;h++){
    union { u16 s[8]; uint4 v; } pk;
    #pragma unroll
    for(int q=0;q<8;q++) pk.s[q] = f2bf(y[h*8+q] + add);
    ((uint4*)p)[h] = pk.v;
  }
}

__global__ __launch_bounds__(256) void k1_dsc(
    const float* __restrict__ x, const float* __restrict__ mask_, const float* __restrict__ avg,
    const float* __restrict__ dwq, const float* __restrict__ dbq,
    const float* __restrict__ dwk, const float* __restrict__ dbk,
    const float* __restrict__ pwk, const float* __restrict__ pbk,
    const float* __restrict__ dwv, const float* __restrict__ dbv,
    u16* __restrict__ Dqx, u16* __restrict__ Dqm, u16* __restrict__ Kx, u16* __restrict__ DvsT)
{
  __shared__ __align__(16) float dwkL[64*68];   // reused as dvsL after pointwise
  __shared__ __align__(16) float pwTL[64*68];
  int t = threadIdx.x;
  int bid = blockIdx.x;
  int tile = bid & 3, iw = (bid>>2)&255, b = bid>>10;

  for(int idx=t; idx<4096; idx+=256)
    pwTL[(idx&63)*68 + (idx>>6)] = pwk[idx];   // pwT[a][o] = pw[o][a]

  int ch = t>>2, pg = t&3;
  int ih0 = tile*64 + pg*16;
  bool leftv = ih0 > 0, rightv = ih0 < 240;
  long base = ((long)(b*64+ch)<<16) + (iw<<8) + ih0;
  bool r0v = iw > 0, r2v = iw < 255;

  float rx[3][18];
  load_row18(x + base - 256, r0v, leftv, rightv, rx[0]);
  load_row18(x + base,       true, leftv, rightv, rx[1]);
  load_row18(x + base + 256, r2v, leftv, rightv, rx[2]);
  float y[16];
  { float w[9];
    #pragma unroll
    for(int q=0;q<9;q++) w[q]=dwq[ch*9+q];
    conv16(rx, w, y); store16bf(Dqx + base, y, dbq[ch]); }
  { float w[9];
    #pragma unroll
    for(int q=0;q<9;q++) w[q]=dwk[ch*9+q];
    conv16(rx, w, y);
    float bk = dbk[ch];
    #pragma unroll
    for(int p=0;p<16;p++) dwkL[ch*68 + pg*16 + p] = y[p] + bk; }
  // x + avg_ct  -> depthwise v (biases doubled: v_x + v_a); keep in regs
  float yv[16];
  load_row18_add(avg + base - 256, r0v, leftv, rightv, rx[0]);
  load_row18_add(avg + base,       true, leftv, rightv, rx[1]);
  load_row18_add(avg + base + 256, r2v, leftv, rightv, rx[2]);
  { float w[9];
    #pragma unroll
    for(int q=0;q<9;q++) w[q]=dwv[ch*9+q];
    conv16(rx, w, yv);
    float bv = 2.f*dbv[ch];
    #pragma unroll
    for(int p=0;p<16;p++) yv[p] += bv; }
  // mask -> depthwise q
  load_row18(mask_ + base - 256, r0v, leftv, rightv, rx[0]);
  load_row18(mask_ + base,       true, leftv, rightv, rx[1]);
  load_row18(mask_ + base + 256, r2v, leftv, rightv, rx[2]);
  { float w[9];
    #pragma unroll
    for(int q=0;q<9;q++) w[q]=dwq[ch*9+q];
    conv16(rx, w, y); store16bf(Dqm + base, y, dbq[ch]); }

  __syncthreads();
  // pointwise 64x64 for k_x only
  int o0 = (t>>4)*4, px0 = (t&15)*4;
  float acc[4][4];
  #pragma unroll
  for(int oo=0;oo<4;oo++){ float pb = pbk[o0+oo];
    #pragma unroll
    for(int pp=0;pp<4;pp++) acc[oo][pp]=pb; }
  for(int a=0;a<64;a++){
    float4 pv4 = *(const float4*)(pwTL + a*68 + o0);
    float4 dv4 = *(const float4*)(dwkL + a*68 + px0);
    float pv[4]={pv4.x,pv4.y,pv4.z,pv4.w};
    float dv[4]={dv4.x,dv4.y,dv4.z,dv4.w};
    #pragma unroll
    for(int oo=0;oo<4;oo++)
      #pragma unroll
      for(int pp=0;pp<4;pp++) acc[oo][pp] = fmaf(pv[oo], dv[pp], acc[oo][pp]);
  }
  #pragma unroll
  for(int oo=0;oo<4;oo++){
    union{ u16 s[4]; uint2 v; } pk;
    #pragma unroll
    for(int pp=0;pp<4;pp++) pk.s[pp] = f2bf(acc[oo][pp]);
    long kb = ((long)(b*64+o0+oo)<<16) + (iw<<8) + tile*64 + px0;
    *(uint2*)(Kx + kb) = pk.v;
  }

  // ---- Dvs transpose through LDS: write DvsT[b][s][ch] (MFMA-B-friendly) ----
  __syncthreads();                 // everyone done reading dwkL
  float* dvsL = dwkL;
  #pragma unroll
  for(int p=0;p<16;p++) dvsL[(pg*16+p)*68 + ch] = yv[p];
  __syncthreads();
  { int sl = t>>2, c0 = (t&3)*16;
    const float4* rp = (const float4*)(dvsL + sl*68 + c0);
    float4 v0=rp[0], v1=rp[1], v2=rp[2], v3=rp[3];
    float f[16] = {v0.x,v0.y,v0.z,v0.w, v1.x,v1.y,v1.z,v1.w,
                   v2.x,v2.y,v2.z,v2.w, v3.x,v3.y,v3.z,v3.w};
    union{ u16 s[8]; uint4 v; } pa, pb2;
    #pragma unroll
    for(int q=0;q<8;q++){ pa.s[q]=f2bf(f[q]); pb2.s[q]=f2bf(f[8+q]); }
    long db = ((long)b<<22) + (long)((iw<<8) + tile*64 + sl)*64 + c0;
    ((uint4*)(DvsT + db))[0] = pa.v;
    ((uint4*)(DvsT + db))[1] = pb2.v;
  }
}

// ---------------- K2: scrambled QK GEMMs via MFMA, per-block partials ----------------
__global__ __launch_bounds__(256) void k2_qk(
    const u16* __restrict__ Dqx, const u16* __restrict__ Dqm, const u16* __restrict__ Kx,
    float* __restrict__ part, float* __restrict__ part_r)
{
  __shared__ u32 bt[64*33];     // B tile, transposed, bf16-pairs packed in u32
  int t = threadIdx.x;
  int pb = blockIdx.x;
  int uh = pb & 1, ch = (pb>>1)&63, b = pb>>7;
  int w = t>>6, lane = t&63;
  int quad = lane>>4, n = lane&15;

  f32x4 z = {0.f,0.f,0.f,0.f};
  f32x4 acc1[4] = {z,z,z,z};
  f32x4 acc2[4] = {z,z,z,z};
  float rs[4] = {0.f,0.f,0.f,0.f};

  long aoff = ((long)(b*64 + w*16 + n)<<16) + ch*1024 + uh*512 + quad*8;
  const u16* A1 = Dqx + aoff;
  const u16* A2 = Dqm + aoff;
  const u16* Bg = Kx + ((long)(b*64+ch)<<16) + (long)(uh*512)*64;
  int r2 = t>>3, c0s = (t&7)*8;

  for(int cu=0; cu<8; cu++){
    const u16* src = Bg + cu*4096;
    uint4 ra = *(const uint4*)(src + (2*r2)*64 + c0s);
    uint4 rb = *(const uint4*)(src + (2*r2+1)*64 + c0s);
    if(cu) __syncthreads();
    { u32 aw[4] = {ra.x,ra.y,ra.z,ra.w};
      u32 bw[4] = {rb.x,rb.y,rb.z,rb.w};
      #pragma unroll
      for(int k=0;k<4;k++){
        u32 lo = (aw[k]&0xffffu) | (bw[k]<<16);
        u32 hi = (aw[k]>>16) | (bw[k]&0xffff0000u);
        int c = c0s + 2*k;
        bt[c*33 + r2]     = lo;
        bt[(c+1)*33 + r2] = hi;
      } }
    __syncthreads();
    #pragma unroll
    for(int ks=0; ks<2; ks++){
      int koff = cu*64 + ks*32;
      short8 a1 = *(const short8*)(A1 + koff);
      short8 a2 = *(const short8*)(A2 + koff);
      #pragma unroll
      for(int c=0;c<4;c++){
        union{ u32 wv[4]; short8 v; } bf;
        #pragma unroll
        for(int i=0;i<4;i++) bf.wv[i] = bt[(c*16+n)*33 + ks*16 + quad*4 + i];
        acc1[c] = __builtin_amdgcn_mfma_f32_16x16x32_bf16(a1, bf.v, acc1[c], 0,0,0);
        acc2[c] = __builtin_amdgcn_mfma_f32_16x16x32_bf16(a2, bf.v, acc2[c], 0,0,0);
        if(w==0){
          #pragma unroll
          for(int i=0;i<4;i++) rs[c] += bf2f(bf.wv[i]&0xffffu) + bf2f(bf.wv[i]>>16);
        }
      }
    }
  }
  float* p1 = part + (long)pb*8192;
  float* p2 = p1 + 4096;
  #pragma unroll
  for(int c=0;c<4;c++)
    #pragma unroll
    for(int r=0;r<4;r++){
      int ar = w*16 + quad*4 + r;
      p1[ar*64 + c*16 + n] = acc1[c][r];
      p2[ar*64 + c*16 + n] = acc2[c][r];
    }
  if(w==0){
    #pragma unroll
    for(int c=0;c<4;c++){
      rs[c] += __shfl_xor(rs[c], 16);
      rs[c] += __shfl_xor(rs[c], 32);
    }
    if(lane < 16){
      #pragma unroll
      for(int c=0;c<4;c++) part_r[(long)pb*64 + c*16 + lane] = rs[c];
    }
  }
}

// ---------------- K2b: reduce partials ----------------
__global__ __launch_bounds__(256) void k2b_reduce(
    const float* __restrict__ part, const float* __restrict__ part_r,
    float* __restrict__ M1, float* __restrict__ M2, float* __restrict__ rsum)
{
  int t = threadIdx.x;
  int blk = blockIdx.x;
  if(blk < 256){
    int e = blk*256 + t;
    int mat = e >> 15;
    int b = (e >> 12) & 7;
    int ij = e & 4095;
    float s = 0.f;
    const float* p = part + ((long)b*256 + mat)*4096 + ij;
    for(int cu=0; cu<128; cu++) s += p[(long)cu*8192];
    (mat ? M2 : M1)[b*4096 + ij] = s;
  } else {
    for(int e=t; e<512; e+=256){
      int bb = e>>6, j = e&63;
      float s=0.f;
      const float* p = part_r + (long)bb*8192 + j;
      for(int cu=0;cu<128;cu++) s += p[cu*64];
      rsum[bb*64 + j] = s;
    }
  }
}

// ---------------- K3: bias fixups + flat softmax + S=A1+A2, T=S*PWv (bf16) ----------------
__global__ __launch_bounds__(256) void k3_small(
    const float* __restrict__ M1, const float* __restrict__ M2, const float* __restrict__ rsum,
    const float* __restrict__ pwq, const float* __restrict__ pbq,
    const float* __restrict__ pwv, const float* __restrict__ pbv,
    u16* __restrict__ Tb, float* __restrict__ cvec)
{
  __shared__ __align__(16) float ML[64*68];
  __shared__ __align__(16) float SL[64*68];
  __shared__ float red[8];
  __shared__ float rL[64];
  int b = blockIdx.x, t = threadIdx.x;
  if(t < 64) rL[t] = rsum[b*64 + t];
  int i = t>>2, j0 = (t&3)*16;
  float pq = pbq[i];
  for(int m=0; m<2; m++){
    const float* M = (m ? M2 : M1) + b*4096;
    __syncthreads();
    for(int idx=t; idx<4096; idx+=256)
      ML[(idx>>6)*68 + (idx&63)] = M[idx];
    __syncthreads();
    float l[16];
    #pragma unroll
    for(int q=0;q<16;q++) l[q] = pq * rL[j0+q];
    for(int a=0;a<64;a++){
      float w = pwq[i*64 + a];
      #pragma unroll
      for(int q=0;q<16;q++) l[q] = fmaf(w, ML[a*68 + j0 + q], l[q]);
    }
    float mx = -1e30f;
    #pragma unroll
    for(int q=0;q<16;q++){ l[q] *= 0.00390625f; mx = fmaxf(mx, l[q]); }
    for(int off=1; off<64; off<<=1) mx = fmaxf(mx, __shfl_xor(mx, off));
    if((t&63)==0) red[t>>6] = mx;
    __syncthreads();
    mx = fmaxf(fmaxf(red[0],red[1]), fmaxf(red[2],red[3]));
    float e[16]; float s = 0.f;
    #pragma unroll
    for(int q=0;q<16;q++){ e[q] = __expf(l[q]-mx); s += e[q]; }
    for(int off=1; off<64; off<<=1) s += __shfl_xor(s, off);
    if((t&63)==0) red[4 + (t>>6)] = s;
    __syncthreads();
    float inv = 1.f / (red[4]+red[5]+red[6]+red[7]);
    if(m==0){
      #pragma unroll
      for(int q=0;q<16;q++) SL[i*68 + j0 + q] = e[q]*inv;
    } else {
      #pragma unroll
      for(int q=0;q<16;q++) SL[i*68 + j0 + q] += e[q]*inv;
    }
  }
  __syncthreads();
  int a0 = (t&3)*16;
  float tacc[16];
  #pragma unroll
  for(int q=0;q<16;q++) tacc[q]=0.f;
  float cv = 0.f;
  for(int j=0;j<64;j++){
    float sij = SL[i*68 + j];
    const float* pr = pwv + j*64 + a0;
    #pragma unroll
    for(int q=0;q<16;q++) tacc[q] = fmaf(sij, pr[q], tacc[q]);
    cv = fmaf(sij, pbv[j], cv);
  }
  { union{ u16 s[8]; uint4 v; } pa, pb2;
    #pragma unroll
    for(int q=0;q<8;q++){ pa.s[q]=f2bf(tacc[q]); pb2.s[q]=f2bf(tacc[8+q]); }
    ((uint4*)(Tb + b*4096 + i*64 + a0))[0] = pa.v;
    ((uint4*)(Tb + b*4096 + i*64 + a0))[1] = pb2.v;
  }
  if((t&3)==0) cvec[b*64 + i] = 2.f*cv;
}

// ---------------- K4: out = T*Dvs + cvec + x via MFMA ----------------
__global__ __launch_bounds__(256) void k4_out(
    const u16* __restrict__ DvsT, const u16* __restrict__ Tb, const float* __restrict__ cvec,
    const float* __restrict__ x, float* __restrict__ out)
{
  __shared__ float cvL[64];
  int t = threadIdx.x;
  int bid = blockIdx.x;
  int sc = bid & 511, b = bid >> 9;
  int s0 = sc * 128;
  if(t < 64) cvL[t] = cvec[b*64 + t];
  __syncthreads();
  int w = t>>6, lane = t&63;
  int quad = lane>>4, n = lane&15;
  const u16* Ap = Tb + b*4096 + (w*16 + n)*64 + quad*8;
  short8 a0 = *(const short8*)(Ap);
  short8 a1 = *(const short8*)(Ap + 32);
  const u16* Bp = DvsT + ((long)b<<22) + (long)(s0 + n)*64 + quad*8;
  #pragma unroll
  for(int c=0;c<8;c++){
    short8 b0 = *(const short8*)(Bp + c*1024);
    short8 b1 = *(const short8*)(Bp + c*1024 + 32);
    f32x4 acc = {0.f,0.f,0.f,0.f};
    acc = __builtin_amdgcn_mfma_f32_16x16x32_bf16(a0, b0, acc, 0,0,0);
    acc = __builtin_amdgcn_mfma_f32_16x16x32_bf16(a1, b1, acc, 0,0,0);
    int scol = s0 + c*16 + n;
    #pragma unroll
    for(int r=0;r<4;r++){
      int i = w*16 + quad*4 + r;
      long g = ((long)(b*64+i)<<16) + scol;
      out[g] = acc[r] + cvL[i] + x[g];
    }
  }
}

extern "C" void kernel_launch(void* const* d_in, const int* in_sizes, int n_in,
                              void* d_out, int out_size, void* d_ws, size_t ws_size,
                              hipStream_t stream)
{
  const float* x    = (const float*)d_in[0];
  const float* mask = (const float*)d_in[1];
  const float* avg  = (const float*)d_in[2];
  const float* dwq  = (const float*)d_in[3];
  const float* dbq  = (const float*)d_in[4];
  const float* pwq  = (const float*)d_in[5];
  const float* pbq  = (const float*)d_in[6];
  const float* dwk  = (const float*)d_in[7];
  const float* dbk  = (const float*)d_in[8];
  const float* pwk  = (const float*)d_in[9];
  const float* pbk  = (const float*)d_in[10];
  const float* dwv  = (const float*)d_in[11];
  const float* dbv  = (const float*)d_in[12];
  const float* pwv  = (const float*)d_in[13];
  const float* pbv  = (const float*)d_in[14];
  float* out = (float*)d_out;
  char* ws = (char*)d_ws;

  u16* Dqx      = (u16*)(ws);
  u16* Dqm      = (u16*)(ws + 67108864);
  u16* Kx       = (u16*)(ws + 134217728);
  u16* DvsT     = (u16*)(ws + 201326592);
  float* part   = (float*)(ws + 268435456);  // 1024 blocks x 2 x 4096 fp32
  float* part_r = (float*)(ws + 301989888);  // 1024 x 64
  float* M1     = (float*)(ws + 302252032);
  float* M2     = (float*)(ws + 302383104);
  float* rsum   = (float*)(ws + 302514176);
  u16*   Tb     = (u16*)(ws + 302516224);    // 8 x 64 x 64 bf16
  float* cvec   = (float*)(ws + 302581760);

  hipLaunchKernelGGL(k1_dsc, dim3(8192), dim3(256), 0, stream,
      x, mask, avg, dwq, dbq, dwk, dbk, pwk, pbk, dwv, dbv, Dqx, Dqm, Kx, DvsT);
  hipLaunchKernelGGL(k2_qk, dim3(1024), dim3(256), 0, stream, Dqx, Dqm, Kx, part, part_r);
  hipLaunchKernelGGL(k2b_reduce, dim3(257), dim3(256), 0, stream, part, part_r, M1, M2, rsum);
  hipLaunchKernelGGL(k3_small, dim3(8), dim3(256), 0, stream, M1, M2, rsum, pwq, pbq, pwv, pbv, Tb, cvec);
  hipLaunchKernelGGL(k4_out, dim3(4096), dim3(256), 0, stream, DvsT, Tb, cvec, x, out);
}